// Round 10
// baseline (396.217 us; speedup 1.0000x reference)
//
#include <hip/hip_runtime.h>
#include <hip/hip_bf16.h>

// B=2, T=2048, C=2048, H=16, HD=128
#define B_  2
#define T_  2048
#define C_  2048
#define H_  16
#define HD_ 128

using bf16x8 = __attribute__((ext_vector_type(8))) __bf16;
using f32x4  = __attribute__((ext_vector_type(4))) float;

__device__ __forceinline__ unsigned short f2bs(float f) {
    __hip_bfloat16 h = __float2bfloat16(f);
    return __builtin_bit_cast(unsigned short, h);
}

// max of 3 — shaped so clang can fuse to v_max3_f32
__device__ __forceinline__ float m3(float a, float b, float c) {
    return fmaxf(fmaxf(a, b), c);
}

// async global->LDS, 16B per lane; LDS dest = wave-uniform base + lane*16
__device__ __forceinline__ void gload_lds16(const unsigned short* g, unsigned short* l) {
    __builtin_amdgcn_global_load_lds(
        (const __attribute__((address_space(1))) unsigned int*)g,
        (__attribute__((address_space(3))) unsigned int*)l, 16, 0, 0);
}

// ---------------- merged prep: fp32->bf16 convert + 2 weight transposes ----------------
// blocks [0,8192): x convert; [8192,11264): Wqkv^T; [11264,12288): Wproj^T
__global__ __launch_bounds__(256) void k_prep(const float* __restrict__ x,
                                              unsigned short* __restrict__ XB,
                                              const float* __restrict__ Wqkv,
                                              unsigned short* __restrict__ WQKVT,
                                              const float* __restrict__ Wproj,
                                              unsigned short* __restrict__ WPROJT) {
    __shared__ unsigned short t[64][65];
    int blk = blockIdx.x;
    int tid = threadIdx.x;
    if (blk < 8192) {
        int i = blk * 256 + tid;
        float4 v = reinterpret_cast<const float4*>(x)[i];
        ushort4 o;
        o.x = f2bs(v.x); o.y = f2bs(v.y); o.z = f2bs(v.z); o.w = f2bs(v.w);
        reinterpret_cast<ushort4*>(XB)[i] = o;
        return;
    }
    const float* in;
    unsigned short* out;
    int K = 2048, N, bx, by;
    if (blk < 11264) {
        in = Wqkv; out = WQKVT; N = 6144;
        bx = (blk - 8192) % 96; by = (blk - 8192) / 96;
    } else {
        in = Wproj; out = WPROJT; N = 2048;
        bx = (blk - 11264) % 32; by = (blk - 11264) / 32;
    }
    int k0 = by * 64, n0 = bx * 64;
#pragma unroll
    for (int p = 0; p < 4; ++p) {
        int idx = p * 256 + tid;
        int r = idx >> 4, c = (idx & 15) << 2;
        float4 v = *reinterpret_cast<const float4*>(in + (long)(k0 + r) * N + n0 + c);
        t[r][c] = f2bs(v.x); t[r][c + 1] = f2bs(v.y);
        t[r][c + 2] = f2bs(v.z); t[r][c + 3] = f2bs(v.w);
    }
    __syncthreads();
#pragma unroll
    for (int p = 0; p < 4; ++p) {
        int idx = p * 256 + tid;
        int r = idx >> 4, c = (idx & 15) << 2;
        ushort4 o;
        o.x = t[c][r]; o.y = t[c + 1][r]; o.z = t[c + 2][r]; o.w = t[c + 3][r];
        *reinterpret_cast<ushort4*>(out + (long)(n0 + r) * K + k0 + c) = o;
    }
}

// ---------------- GEMM: A[M][K] bf16 x Bt[N][K] bf16 -> epilogue per MODE ----------------
// 128x128 tile, BK=64 as two BK=32 sub-buffers — m97 structure, EXACT r4/r7 version.
// Session evidence (r1, r5, r8): every source-level reorder of stage/compute regressed;
// __syncthreads' vmcnt(0) drain makes fewer-bigger drains optimal, and counted-vmcnt
// pipelining is not reachable from this structure at HIP level. DO NOT re-reorder.
// MODE 0: write qkv, Q/K as [bh][T][HD], V transposed as [bh][HD][T].
// MODE 1: out fp32 [M][N] + bias.
template <int MODE>
__global__ __launch_bounds__(256, 2) void k_gemm(const unsigned short* __restrict__ A,
                                                 const unsigned short* __restrict__ Bt,
                                                 int M, int N, int K,
                                                 unsigned short* __restrict__ qkv,
                                                 float* __restrict__ out,
                                                 const float* __restrict__ bias) {
    __shared__ __align__(16) unsigned short lA[2][128 * 32];
    __shared__ __align__(16) unsigned short lB[2][128 * 32];

    int tid = threadIdx.x;
    int wave = tid >> 6, lane = tid & 63;
    int quad = lane >> 4, l16 = lane & 15;
    int wr = (wave >> 1) * 64, wc = (wave & 1) * 64;
    int m0 = blockIdx.y * 128, n0 = blockIdx.x * 128;

    int lrow = lane >> 2;          // 0..15
    int lcol = (lane & 3) << 3;    // 0,8,16,24
    const unsigned short* gA0 = A + (long)(m0 + wave * 32 + lrow) * K + lcol;
    const unsigned short* gA1 = A + (long)(m0 + wave * 32 + 16 + lrow) * K + lcol;
    const unsigned short* gB0 = Bt + (long)(n0 + wave * 32 + lrow) * K + lcol;
    const unsigned short* gB1 = Bt + (long)(n0 + wave * 32 + 16 + lrow) * K + lcol;
    int lofs0 = wave * 1024, lofs1 = wave * 1024 + 512;

    f32x4 zero = {0.f, 0.f, 0.f, 0.f};
    f32x4 acc[4][4];
#pragma unroll
    for (int i = 0; i < 4; ++i)
#pragma unroll
        for (int j = 0; j < 4; ++j) acc[i][j] = zero;

    for (int k0 = 0; k0 < K; k0 += 64) {
        __syncthreads();
#pragma unroll
        for (int h = 0; h < 2; ++h) {
            int kk = k0 + h * 32;
            gload_lds16(gA0 + kk, &lA[h][lofs0]);
            gload_lds16(gA1 + kk, &lA[h][lofs1]);
            gload_lds16(gB0 + kk, &lB[h][lofs0]);
            gload_lds16(gB1 + kk, &lB[h][lofs1]);
        }
        __syncthreads();  // single vmcnt(0) drain per 32 MFMA
#pragma unroll
        for (int h = 0; h < 2; ++h) {
            bf16x8 af[4], bfr[4];
#pragma unroll
            for (int i = 0; i < 4; ++i)
                af[i] = *reinterpret_cast<const bf16x8*>(&lA[h][(wr + i * 16 + l16) * 32 + quad * 8]);
#pragma unroll
            for (int j = 0; j < 4; ++j)
                bfr[j] = *reinterpret_cast<const bf16x8*>(&lB[h][(wc + j * 16 + l16) * 32 + quad * 8]);
#pragma unroll
            for (int i = 0; i < 4; ++i)
#pragma unroll
                for (int j = 0; j < 4; ++j)
                    acc[i][j] = __builtin_amdgcn_mfma_f32_16x16x32_bf16(af[i], bfr[j], acc[i][j], 0, 0, 0);
        }
    }

#pragma unroll
    for (int i = 0; i < 4; ++i) {
#pragma unroll
        for (int j = 0; j < 4; ++j) {
#pragma unroll
            for (int r = 0; r < 4; ++r) {
                int m = m0 + wr + i * 16 + quad * 4 + r;
                int n = n0 + wc + j * 16 + l16;
                float v = acc[i][j][r];
                if (MODE == 0) {
                    int s = n >> 11, col = n & 2047;
                    int h = col >> 7, hd = col & 127;
                    int b = m >> 11, t = m & 2047;
                    long base = (long)s * (B_ * H_ * T_ * HD_);
                    if (s == 2)  // V stored transposed: [bh][HD][T]
                        qkv[base + ((long)(b * H_ + h) * HD_ + hd) * T_ + t] = f2bs(v);
                    else
                        qkv[base + ((long)(b * H_ + h) * T_ + t) * HD_ + hd] = f2bs(v);
                } else {
                    out[(long)m * N + n] = v + bias[n];
                }
            }
        }
    }
}

// ---------------- flash attention (v9: v8 + exp2-domain softmax + max3 tree) ----------------
// qkv: Q,K [bh][T][HD], V [bh][HD][T] (pre-transposed), all bf16 -> y [B*T][C] bf16
// block: 4 waves, 128 q-rows (32/wave as TWO 16-row groups), kv-step 64.
// Grid (bh=32, 16) with complementary heavy/light tile pairing (r7-verified).
// v9: softmax in exp2 domain — scl2 = (1/sqrt(128))*log2(e) folded into the scale,
// exp2f maps to native v_exp_f32 (saves 32 muls/step/group); P values identical:
// 2^(s*scl*log2e - m*log2e) == e^(s*scl - m). Defer threshold 11.5 (== e^8 bound).
// Max reduction restructured as a max3-fusible tree (v_max3_f32).
__global__ __launch_bounds__(256, 2) void k_attn(const unsigned short* __restrict__ qkv,
                                                 unsigned short* __restrict__ y) {
    __shared__ __align__(16) unsigned short lK[64 * 136];      // [key][hd], stride 136
    __shared__ __align__(16) unsigned short lVt[128 * 72];     // [hd][key], stride 72
    __shared__ __align__(16) unsigned short lP[4][2][16 * 72]; // per-wave, per-group P

    int tid = threadIdx.x;
    int wave = tid >> 6, lane = tid & 63;
    int quad = lane >> 4, l16 = lane & 15;
    int bh = blockIdx.x;                                    // 0..31
    int ty = (int)blockIdx.y;
    int tile = (ty < 8) ? (15 - ty) : (ty - 8);             // balanced heavy/light pairing
    int qb = tile * 128;

    const unsigned short* Qh = qkv + (long)bh * (T_ * HD_);
    const unsigned short* Kh = qkv + (long)(B_ * H_) * T_ * HD_ + (long)bh * (T_ * HD_);
    const unsigned short* Vt = qkv + 2L * (B_ * H_) * T_ * HD_ + (long)bh * (HD_ * T_);

    // preload this wave's 32 Q rows (2 groups of 16) as B-fragments
    bf16x8 aQ0[4], aQ1[4];
    const int q0_abs = qb + wave * 32 + l16;       // group-0 row owned by this lane
    const int q1_abs = q0_abs + 16;                // group-1 row
#pragma unroll
    for (int kk = 0; kk < 4; ++kk) {
        aQ0[kk] = *reinterpret_cast<const bf16x8*>(Qh + (long)q0_abs * HD_ + kk * 32 + quad * 8);
        aQ1[kk] = *reinterpret_cast<const bf16x8*>(Qh + (long)q1_abs * HD_ + kk * 32 + quad * 8);
    }

    // per-thread staging coordinates (fixed): K: 4 chunks of 16B, V: 4 chunks
    const int kR0 = tid >> 4, kC = (tid & 15) << 3;   // K rows tid>>4 + {0,16,32,48}
    const int vR0 = tid >> 3, vC = (tid & 7) << 3;    // V rows tid>>3 + {0,32,64,96}

    // T14 prefetch registers — NAMED scalars, never arrays (spill-proof, r3 lesson)
    int4 kr0, kr1, kr2, kr3, vr0, vr1, vr2, vr3;
    {
        long ko = 0;
        kr0 = *reinterpret_cast<const int4*>(Kh + (ko + kR0)      * HD_ + kC);
        kr1 = *reinterpret_cast<const int4*>(Kh + (ko + kR0 + 16) * HD_ + kC);
        kr2 = *reinterpret_cast<const int4*>(Kh + (ko + kR0 + 32) * HD_ + kC);
        kr3 = *reinterpret_cast<const int4*>(Kh + (ko + kR0 + 48) * HD_ + kC);
        vr0 = *reinterpret_cast<const int4*>(Vt + (long)(vR0)      * T_ + ko + vC);
        vr1 = *reinterpret_cast<const int4*>(Vt + (long)(vR0 + 32) * T_ + ko + vC);
        vr2 = *reinterpret_cast<const int4*>(Vt + (long)(vR0 + 64) * T_ + ko + vC);
        vr3 = *reinterpret_cast<const int4*>(Vt + (long)(vR0 + 96) * T_ + ko + vC);
    }

    float m0_ = -1e30f, l0_ = 0.f, m1_ = -1e30f, l1_ = 0.f;
    f32x4 O0[8], O1[8];
    f32x4 zero = {0.f, 0.f, 0.f, 0.f};
#pragma unroll
    for (int h = 0; h < 8; ++h) { O0[h] = zero; O1[h] = zero; }

    const float scl2 = 0.12751743f;   // (1/sqrt(128)) * log2(e) — exp2-domain scale
    const float THR  = 11.5f;         // defer-max threshold in log2 units (~= e^8)
    const int kbend = qb + 128;
    const int qmaxw = qb + wave * 32 + 31;   // wave-uniform causal bound

    for (int kb = 0; kb < kbend; kb += 64) {
        // syncA: all waves done reading previous tile; drains prefetch issued a
        // full compute-phase ago (cheap).
        __syncthreads();

        // reg -> LDS
        *reinterpret_cast<int4*>(&lK[(kR0)      * 136 + kC]) = kr0;
        *reinterpret_cast<int4*>(&lK[(kR0 + 16) * 136 + kC]) = kr1;
        *reinterpret_cast<int4*>(&lK[(kR0 + 32) * 136 + kC]) = kr2;
        *reinterpret_cast<int4*>(&lK[(kR0 + 48) * 136 + kC]) = kr3;
        *reinterpret_cast<int4*>(&lVt[(vR0)      * 72 + vC]) = vr0;
        *reinterpret_cast<int4*>(&lVt[(vR0 + 32) * 72 + vC]) = vr1;
        *reinterpret_cast<int4*>(&lVt[(vR0 + 64) * 72 + vC]) = vr2;
        *reinterpret_cast<int4*>(&lVt[(vR0 + 96) * 72 + vC]) = vr3;

        // syncB: LDS writes visible; zero outstanding VMEM here -> drain is free
        __syncthreads();

        // issue next tile's prefetch NOW — lands during this step's compute
        {
            int nkb = kb + 64;
            long ko = (nkb < kbend) ? nkb : 0;  // clamp keeps last-iter loads in-bounds
            kr0 = *reinterpret_cast<const int4*>(Kh + (ko + kR0)      * HD_ + kC);
            kr1 = *reinterpret_cast<const int4*>(Kh + (ko + kR0 + 16) * HD_ + kC);
            kr2 = *reinterpret_cast<const int4*>(Kh + (ko + kR0 + 32) * HD_ + kC);
            kr3 = *reinterpret_cast<const int4*>(Kh + (ko + kR0 + 48) * HD_ + kC);
            vr0 = *reinterpret_cast<const int4*>(Vt + (long)(vR0)      * T_ + ko + vC);
            vr1 = *reinterpret_cast<const int4*>(Vt + (long)(vR0 + 32) * T_ + ko + vC);
            vr2 = *reinterpret_cast<const int4*>(Vt + (long)(vR0 + 64) * T_ + ko + vC);
            vr3 = *reinterpret_cast<const int4*>(Vt + (long)(vR0 + 96) * T_ + ko + vC);
        }

        if (kb > qmaxw) continue;  // wave-uniform skip; barriers stay at loop top

        // wave-uniform: tile entirely below the diagonal for this group?
        const bool full0 = (kb + 63) <= (qb + wave * 32);
        const bool full1 = (kb + 63) <= (qb + wave * 32 + 16);

        // S^T = K Q^T for BOTH groups; each kf ds_read feeds 2 MFMAs.
        // s{g}[st][r] = S[key=kb+st*16+quad*4+r][q{g}_abs]
        f32x4 s0[4], s1[4];
#pragma unroll
        for (int st = 0; st < 4; ++st) { s0[st] = zero; s1[st] = zero; }
#pragma unroll
        for (int kk = 0; kk < 4; ++kk) {
#pragma unroll
            for (int st = 0; st < 4; ++st) {
                bf16x8 kf = *reinterpret_cast<const bf16x8*>(
                    &lK[(st * 16 + l16) * 136 + kk * 32 + quad * 8]);
                s0[st] = __builtin_amdgcn_mfma_f32_16x16x32_bf16(kf, aQ0[kk], s0[st], 0, 0, 0);
                s1[st] = __builtin_amdgcn_mfma_f32_16x16x32_bf16(kf, aQ1[kk], s1[st], 0, 0, 0);
            }
        }

        // ---- online softmax (exp2 domain), group 0 ----
        {
            float xv[4][4];
            if (full0) {
#pragma unroll
                for (int st = 0; st < 4; ++st)
#pragma unroll
                    for (int r = 0; r < 4; ++r) xv[st][r] = s0[st][r] * scl2;
            } else {
#pragma unroll
                for (int st = 0; st < 4; ++st)
#pragma unroll
                    for (int r = 0; r < 4; ++r) {
                        int key = kb + st * 16 + quad * 4 + r;
                        xv[st][r] = (key <= q0_abs) ? s0[st][r] * scl2 : -1e30f;
                    }
            }
            // max3-fusible reduction tree over the 16 values
            float g0 = m3(xv[0][0], xv[0][1], xv[0][2]);
            float g1 = m3(xv[0][3], xv[1][0], xv[1][1]);
            float g2 = m3(xv[1][2], xv[1][3], xv[2][0]);
            float g3 = m3(xv[2][1], xv[2][2], xv[2][3]);
            float g4 = m3(xv[3][0], xv[3][1], xv[3][2]);
            float mx = m3(m3(g0, g1, g2), fmaxf(g3, g4), xv[3][3]);
            mx = fmaxf(mx, __shfl_xor(mx, 16));
            mx = fmaxf(mx, __shfl_xor(mx, 32));
            bool defer = __all(mx - m0_ <= THR);   // T13 defer-max (log2 units)
            float mn = defer ? m0_ : fmaxf(m0_, mx);
            float rs = 0.f;
#pragma unroll
            for (int st = 0; st < 4; ++st)
#pragma unroll
                for (int r = 0; r < 4; ++r) {
                    float e = __builtin_exp2f(xv[st][r] - mn);
                    xv[st][r] = e;
                    rs += e;
                }
            rs += __shfl_xor(rs, 16);
            rs += __shfl_xor(rs, 32);
#pragma unroll
            for (int st = 0; st < 4; ++st) {
                ushort4 pk;
                pk.x = f2bs(xv[st][0]); pk.y = f2bs(xv[st][1]);
                pk.z = f2bs(xv[st][2]); pk.w = f2bs(xv[st][3]);
                *reinterpret_cast<ushort4*>(&lP[wave][0][l16 * 72 + st * 16 + quad * 4]) = pk;
            }
            if (defer) {
                l0_ = l0_ + rs;
            } else {
                float al = __builtin_exp2f(m0_ - mn);
                l0_ = l0_ * al + rs;
                m0_ = mn;
                float alr[4];
#pragma unroll
                for (int r = 0; r < 4; ++r) alr[r] = __shfl(al, quad * 4 + r);
#pragma unroll
                for (int h = 0; h < 8; ++h)
#pragma unroll
                    for (int r = 0; r < 4; ++r) O0[h][r] *= alr[r];
            }
        }
        // ---- online softmax (exp2 domain), group 1 ----
        {
            float xv[4][4];
            if (full1) {
#pragma unroll
                for (int st = 0; st < 4; ++st)
#pragma unroll
                    for (int r = 0; r < 4; ++r) xv[st][r] = s1[st][r] * scl2;
            } else {
#pragma unroll
                for (int st = 0; st < 4; ++st)
#pragma unroll
                    for (int r = 0; r < 4; ++r) {
                        int key = kb + st * 16 + quad * 4 + r;
                        xv[st][r] = (key <= q1_abs) ? s1[st][r] * scl2 : -1e30f;
                    }
            }
            float g0 = m3(xv[0][0], xv[0][1], xv[0][2]);
            float g1 = m3(xv[0][3], xv[1][0], xv[1][1]);
            float g2 = m3(xv[1][2], xv[1][3], xv[2][0]);
            float g3 = m3(xv[2][1], xv[2][2], xv[2][3]);
            float g4 = m3(xv[3][0], xv[3][1], xv[3][2]);
            float mx = m3(m3(g0, g1, g2), fmaxf(g3, g4), xv[3][3]);
            mx = fmaxf(mx, __shfl_xor(mx, 16));
            mx = fmaxf(mx, __shfl_xor(mx, 32));
            bool defer = __all(mx - m1_ <= THR);
            float mn = defer ? m1_ : fmaxf(m1_, mx);
            float rs = 0.f;
#pragma unroll
            for (int st = 0; st < 4; ++st)
#pragma unroll
                for (int r = 0; r < 4; ++r) {
                    float e = __builtin_exp2f(xv[st][r] - mn);
                    xv[st][r] = e;
                    rs += e;
                }
            rs += __shfl_xor(rs, 16);
            rs += __shfl_xor(rs, 32);
#pragma unroll
            for (int st = 0; st < 4; ++st) {
                ushort4 pk;
                pk.x = f2bs(xv[st][0]); pk.y = f2bs(xv[st][1]);
                pk.z = f2bs(xv[st][2]); pk.w = f2bs(xv[st][3]);
                *reinterpret_cast<ushort4*>(&lP[wave][1][l16 * 72 + st * 16 + quad * 4]) = pk;
            }
            if (defer) {
                l1_ = l1_ + rs;
            } else {
                float al = __builtin_exp2f(m1_ - mn);
                l1_ = l1_ * al + rs;
                m1_ = mn;
                float alr[4];
#pragma unroll
                for (int r = 0; r < 4; ++r) alr[r] = __shfl(al, quad * 4 + r);
#pragma unroll
                for (int h = 0; h < 8; ++h)
#pragma unroll
                    for (int r = 0; r < 4; ++r) O1[h][r] *= alr[r];
            }
        }

        // P @ V for BOTH groups; each vf ds_read feeds 2 MFMAs.
#pragma unroll
        for (int kc = 0; kc < 2; ++kc) {
            bf16x8 pf0 = *reinterpret_cast<const bf16x8*>(
                &lP[wave][0][l16 * 72 + kc * 32 + quad * 8]);
            bf16x8 pf1 = *reinterpret_cast<const bf16x8*>(
                &lP[wave][1][l16 * 72 + kc * 32 + quad * 8]);
#pragma unroll
            for (int h = 0; h < 8; ++h) {
                bf16x8 vf = *reinterpret_cast<const bf16x8*>(
                    &lVt[(h * 16 + l16) * 72 + kc * 32 + quad * 8]);
                O0[h] = __builtin_amdgcn_mfma_f32_16x16x32_bf16(pf0, vf, O0[h], 0, 0, 0);
                O1[h] = __builtin_amdgcn_mfma_f32_16x16x32_bf16(pf1, vf, O1[h], 0, 0, 0);
            }
        }
    }

    // write y[b*T+t][hh*128 + hd] bf16; 1/l for row quad*4+r fetched from lane l16=quad*4+r
    int b = bh >> 4, hh = bh & 15;
#pragma unroll
    for (int r = 0; r < 4; ++r) {
        int t0 = qb + wave * 32 + quad * 4 + r;
        float inv0 = 1.f / __shfl(l0_, quad * 4 + r);
#pragma unroll
        for (int h = 0; h < 8; ++h)
            y[(long)(b * T_ + t0) * C_ + hh * HD_ + h * 16 + l16] = f2bs(O0[h][r] * inv0);
        int t1 = t0 + 16;
        float inv1 = 1.f / __shfl(l1_, quad * 4 + r);
#pragma unroll
        for (int h = 0; h < 8; ++h)
            y[(long)(b * T_ + t1) * C_ + hh * HD_ + h * 16 + l16] = f2bs(O1[h][r] * inv1);
    }
}

extern "C" void kernel_launch(void* const* d_in, const int* in_sizes, int n_in,
                              void* d_out, int out_size, void* d_ws, size_t ws_size,
                              hipStream_t stream) {
    const float* x     = (const float*)d_in[0];
    // d_in[1] = causal mask, ignored (handled analytically)
    const float* Wqkv  = (const float*)d_in[2];
    const float* Wproj = (const float*)d_in[3];
    const float* bproj = (const float*)d_in[4];
    float* out = (float*)d_out;

    // workspace layout (bf16 elements); y aliases XB (XB dead after gemm1)
    unsigned short* XB     = (unsigned short*)d_ws;   // [4096][2048]  (later: y)
    unsigned short* WQKVT  = XB + 8388608;            // [6144][2048]
    unsigned short* WPROJT = WQKVT + 12582912;        // [2048][2048]
    unsigned short* QKV    = WPROJT + 4194304;        // [3][32][...]
    if (ws_size < 100663296) return;                  // 96 MB needed

    k_prep<<<12288, 256, 0, stream>>>(x, XB, Wqkv, WQKVT, Wproj, WPROJT);
    k_gemm<0><<<dim3(6144 / 128, 4096 / 128), 256, 0, stream>>>(XB, WQKVT, 4096, 6144, 2048,
                                                                QKV, nullptr, nullptr);
    k_attn<<<dim3(32, 16), 256, 0, stream>>>(QKV, XB);
    k_gemm<1><<<dim3(2048 / 128, 4096 / 128), 256, 0, stream>>>(XB, WPROJT, 4096, 2048, 2048,
                                                                nullptr, out, bproj);
}

// Round 11
// 381.697 us; speedup vs baseline: 1.0380x; 1.0380x over previous
//
#include <hip/hip_runtime.h>
#include <hip/hip_bf16.h>

// B=2, T=2048, C=2048, H=16, HD=128
#define B_  2
#define T_  2048
#define C_  2048
#define H_  16
#define HD_ 128

using bf16x8 = __attribute__((ext_vector_type(8))) __bf16;
using f32x4  = __attribute__((ext_vector_type(4))) float;

__device__ __forceinline__ unsigned short f2bs(float f) {
    __hip_bfloat16 h = __float2bfloat16(f);
    return __builtin_bit_cast(unsigned short, h);
}

// async global->LDS, 16B per lane; LDS dest = wave-uniform base + lane*16
__device__ __forceinline__ void gload_lds16(const unsigned short* g, unsigned short* l) {
    __builtin_amdgcn_global_load_lds(
        (const __attribute__((address_space(1))) unsigned int*)g,
        (__attribute__((address_space(3))) unsigned int*)l, 16, 0, 0);
}

// ---------------- merged prep: fp32->bf16 convert + 2 weight transposes ----------------
// blocks [0,8192): x convert; [8192,11264): Wqkv^T; [11264,12288): Wproj^T
__global__ __launch_bounds__(256) void k_prep(const float* __restrict__ x,
                                              unsigned short* __restrict__ XB,
                                              const float* __restrict__ Wqkv,
                                              unsigned short* __restrict__ WQKVT,
                                              const float* __restrict__ Wproj,
                                              unsigned short* __restrict__ WPROJT) {
    __shared__ unsigned short t[64][65];
    int blk = blockIdx.x;
    int tid = threadIdx.x;
    if (blk < 8192) {
        int i = blk * 256 + tid;
        float4 v = reinterpret_cast<const float4*>(x)[i];
        ushort4 o;
        o.x = f2bs(v.x); o.y = f2bs(v.y); o.z = f2bs(v.z); o.w = f2bs(v.w);
        reinterpret_cast<ushort4*>(XB)[i] = o;
        return;
    }
    const float* in;
    unsigned short* out;
    int K = 2048, N, bx, by;
    if (blk < 11264) {
        in = Wqkv; out = WQKVT; N = 6144;
        bx = (blk - 8192) % 96; by = (blk - 8192) / 96;
    } else {
        in = Wproj; out = WPROJT; N = 2048;
        bx = (blk - 11264) % 32; by = (blk - 11264) / 32;
    }
    int k0 = by * 64, n0 = bx * 64;
#pragma unroll
    for (int p = 0; p < 4; ++p) {
        int idx = p * 256 + tid;
        int r = idx >> 4, c = (idx & 15) << 2;
        float4 v = *reinterpret_cast<const float4*>(in + (long)(k0 + r) * N + n0 + c);
        t[r][c] = f2bs(v.x); t[r][c + 1] = f2bs(v.y);
        t[r][c + 2] = f2bs(v.z); t[r][c + 3] = f2bs(v.w);
    }
    __syncthreads();
#pragma unroll
    for (int p = 0; p < 4; ++p) {
        int idx = p * 256 + tid;
        int r = idx >> 4, c = (idx & 15) << 2;
        ushort4 o;
        o.x = t[c][r]; o.y = t[c + 1][r]; o.z = t[c + 2][r]; o.w = t[c + 3][r];
        *reinterpret_cast<ushort4*>(out + (long)(n0 + r) * K + k0 + c) = o;
    }
}

// ---------------- GEMM: A[M][K] bf16 x Bt[N][K] bf16 -> epilogue per MODE ----------------
// 128x128 tile, BK=64 as two BK=32 sub-buffers — m97 structure, EXACT r4/r7 version.
// Session evidence (r1, r5, r8): every source-level reorder of stage/compute regressed;
// __syncthreads' vmcnt(0) drain makes fewer-bigger drains optimal, and counted-vmcnt
// pipelining is not reachable from this structure at HIP level. DO NOT re-reorder.
// MODE 0: write qkv, Q/K as [bh][T][HD], V transposed as [bh][HD][T].
// MODE 1: out fp32 [M][N] + bias.
template <int MODE>
__global__ __launch_bounds__(256, 2) void k_gemm(const unsigned short* __restrict__ A,
                                                 const unsigned short* __restrict__ Bt,
                                                 int M, int N, int K,
                                                 unsigned short* __restrict__ qkv,
                                                 float* __restrict__ out,
                                                 const float* __restrict__ bias) {
    __shared__ __align__(16) unsigned short lA[2][128 * 32];
    __shared__ __align__(16) unsigned short lB[2][128 * 32];

    int tid = threadIdx.x;
    int wave = tid >> 6, lane = tid & 63;
    int quad = lane >> 4, l16 = lane & 15;
    int wr = (wave >> 1) * 64, wc = (wave & 1) * 64;
    int m0 = blockIdx.y * 128, n0 = blockIdx.x * 128;

    int lrow = lane >> 2;          // 0..15
    int lcol = (lane & 3) << 3;    // 0,8,16,24
    const unsigned short* gA0 = A + (long)(m0 + wave * 32 + lrow) * K + lcol;
    const unsigned short* gA1 = A + (long)(m0 + wave * 32 + 16 + lrow) * K + lcol;
    const unsigned short* gB0 = Bt + (long)(n0 + wave * 32 + lrow) * K + lcol;
    const unsigned short* gB1 = Bt + (long)(n0 + wave * 32 + 16 + lrow) * K + lcol;
    int lofs0 = wave * 1024, lofs1 = wave * 1024 + 512;

    f32x4 zero = {0.f, 0.f, 0.f, 0.f};
    f32x4 acc[4][4];
#pragma unroll
    for (int i = 0; i < 4; ++i)
#pragma unroll
        for (int j = 0; j < 4; ++j) acc[i][j] = zero;

    for (int k0 = 0; k0 < K; k0 += 64) {
        __syncthreads();
#pragma unroll
        for (int h = 0; h < 2; ++h) {
            int kk = k0 + h * 32;
            gload_lds16(gA0 + kk, &lA[h][lofs0]);
            gload_lds16(gA1 + kk, &lA[h][lofs1]);
            gload_lds16(gB0 + kk, &lB[h][lofs0]);
            gload_lds16(gB1 + kk, &lB[h][lofs1]);
        }
        __syncthreads();  // single vmcnt(0) drain per 32 MFMA
#pragma unroll
        for (int h = 0; h < 2; ++h) {
            bf16x8 af[4], bfr[4];
#pragma unroll
            for (int i = 0; i < 4; ++i)
                af[i] = *reinterpret_cast<const bf16x8*>(&lA[h][(wr + i * 16 + l16) * 32 + quad * 8]);
#pragma unroll
            for (int j = 0; j < 4; ++j)
                bfr[j] = *reinterpret_cast<const bf16x8*>(&lB[h][(wc + j * 16 + l16) * 32 + quad * 8]);
#pragma unroll
            for (int i = 0; i < 4; ++i)
#pragma unroll
                for (int j = 0; j < 4; ++j)
                    acc[i][j] = __builtin_amdgcn_mfma_f32_16x16x32_bf16(af[i], bfr[j], acc[i][j], 0, 0, 0);
        }
    }

#pragma unroll
    for (int i = 0; i < 4; ++i) {
#pragma unroll
        for (int j = 0; j < 4; ++j) {
#pragma unroll
            for (int r = 0; r < 4; ++r) {
                int m = m0 + wr + i * 16 + quad * 4 + r;
                int n = n0 + wc + j * 16 + l16;
                float v = acc[i][j][r];
                if (MODE == 0) {
                    int s = n >> 11, col = n & 2047;
                    int h = col >> 7, hd = col & 127;
                    int b = m >> 11, t = m & 2047;
                    long base = (long)s * (B_ * H_ * T_ * HD_);
                    if (s == 2)  // V stored transposed: [bh][HD][T]
                        qkv[base + ((long)(b * H_ + h) * HD_ + hd) * T_ + t] = f2bs(v);
                    else
                        qkv[base + ((long)(b * H_ + h) * T_ + t) * HD_ + hd] = f2bs(v);
                } else {
                    out[(long)m * N + n] = v + bias[n];
                }
            }
        }
    }
}

// ---------------- flash attention (v8 FINAL: best-verified config, 385.5 us total) ----------------
// qkv: Q,K [bh][T][HD], V [bh][HD][T] (pre-transposed), all bf16 -> y [B*T][C] bf16
// block: 4 waves, 128 q-rows (32/wave as TWO 16-row groups), kv-step 64.
// Grid (bh=32, 16) with complementary heavy/light tile pairing (r7-verified).
// Components, each harness-verified this session:
//  - swapped QK^T (mfma(K,Q)): softmax row-reduce = in-lane fmax chain + 2 shfl (r4)
//  - T14 named-scalar prefetch staging (spill-proof; r4; r3's array form spilled 443MB)
//  - 2-q-group ds_read sharing: 64 MFMA per 36 LDS reads (r6/r7)
//  - complementary tile pairing: constant 36-step work per CU pair (r7)
//  - full-tile causal-mask skip (r8)
//  - T13 defer-max THR=8 (r9, absmax unchanged)
// REJECTED on HW this session: setprio (r5/r6), exp2-domain+max3 (r10, +11us),
// all GEMM schedule reorders (r1/r5/r8).
__global__ __launch_bounds__(256, 2) void k_attn(const unsigned short* __restrict__ qkv,
                                                 unsigned short* __restrict__ y) {
    __shared__ __align__(16) unsigned short lK[64 * 136];      // [key][hd], stride 136
    __shared__ __align__(16) unsigned short lVt[128 * 72];     // [hd][key], stride 72
    __shared__ __align__(16) unsigned short lP[4][2][16 * 72]; // per-wave, per-group P

    int tid = threadIdx.x;
    int wave = tid >> 6, lane = tid & 63;
    int quad = lane >> 4, l16 = lane & 15;
    int bh = blockIdx.x;                                    // 0..31
    int ty = (int)blockIdx.y;
    int tile = (ty < 8) ? (15 - ty) : (ty - 8);             // balanced heavy/light pairing
    int qb = tile * 128;

    const unsigned short* Qh = qkv + (long)bh * (T_ * HD_);
    const unsigned short* Kh = qkv + (long)(B_ * H_) * T_ * HD_ + (long)bh * (T_ * HD_);
    const unsigned short* Vt = qkv + 2L * (B_ * H_) * T_ * HD_ + (long)bh * (HD_ * T_);

    // preload this wave's 32 Q rows (2 groups of 16) as B-fragments
    bf16x8 aQ0[4], aQ1[4];
    const int q0_abs = qb + wave * 32 + l16;       // group-0 row owned by this lane
    const int q1_abs = q0_abs + 16;                // group-1 row
#pragma unroll
    for (int kk = 0; kk < 4; ++kk) {
        aQ0[kk] = *reinterpret_cast<const bf16x8*>(Qh + (long)q0_abs * HD_ + kk * 32 + quad * 8);
        aQ1[kk] = *reinterpret_cast<const bf16x8*>(Qh + (long)q1_abs * HD_ + kk * 32 + quad * 8);
    }

    // per-thread staging coordinates (fixed): K: 4 chunks of 16B, V: 4 chunks
    const int kR0 = tid >> 4, kC = (tid & 15) << 3;   // K rows tid>>4 + {0,16,32,48}
    const int vR0 = tid >> 3, vC = (tid & 7) << 3;    // V rows tid>>3 + {0,32,64,96}

    // T14 prefetch registers — NAMED scalars, never arrays (spill-proof, r3 lesson)
    int4 kr0, kr1, kr2, kr3, vr0, vr1, vr2, vr3;
    {
        long ko = 0;
        kr0 = *reinterpret_cast<const int4*>(Kh + (ko + kR0)      * HD_ + kC);
        kr1 = *reinterpret_cast<const int4*>(Kh + (ko + kR0 + 16) * HD_ + kC);
        kr2 = *reinterpret_cast<const int4*>(Kh + (ko + kR0 + 32) * HD_ + kC);
        kr3 = *reinterpret_cast<const int4*>(Kh + (ko + kR0 + 48) * HD_ + kC);
        vr0 = *reinterpret_cast<const int4*>(Vt + (long)(vR0)      * T_ + ko + vC);
        vr1 = *reinterpret_cast<const int4*>(Vt + (long)(vR0 + 32) * T_ + ko + vC);
        vr2 = *reinterpret_cast<const int4*>(Vt + (long)(vR0 + 64) * T_ + ko + vC);
        vr3 = *reinterpret_cast<const int4*>(Vt + (long)(vR0 + 96) * T_ + ko + vC);
    }

    float m0_ = -1e30f, l0_ = 0.f, m1_ = -1e30f, l1_ = 0.f;
    f32x4 O0[8], O1[8];
    f32x4 zero = {0.f, 0.f, 0.f, 0.f};
#pragma unroll
    for (int h = 0; h < 8; ++h) { O0[h] = zero; O1[h] = zero; }

    const float scl = 0.08838834764831845f;  // 1/sqrt(128)
    const float THR = 8.f;                   // T13 defer-max threshold (HK value)
    const int kbend = qb + 128;
    const int qmaxw = qb + wave * 32 + 31;   // wave-uniform causal bound

    for (int kb = 0; kb < kbend; kb += 64) {
        // syncA: all waves done reading previous tile; drains prefetch issued a
        // full compute-phase ago (cheap).
        __syncthreads();

        // reg -> LDS
        *reinterpret_cast<int4*>(&lK[(kR0)      * 136 + kC]) = kr0;
        *reinterpret_cast<int4*>(&lK[(kR0 + 16) * 136 + kC]) = kr1;
        *reinterpret_cast<int4*>(&lK[(kR0 + 32) * 136 + kC]) = kr2;
        *reinterpret_cast<int4*>(&lK[(kR0 + 48) * 136 + kC]) = kr3;
        *reinterpret_cast<int4*>(&lVt[(vR0)      * 72 + vC]) = vr0;
        *reinterpret_cast<int4*>(&lVt[(vR0 + 32) * 72 + vC]) = vr1;
        *reinterpret_cast<int4*>(&lVt[(vR0 + 64) * 72 + vC]) = vr2;
        *reinterpret_cast<int4*>(&lVt[(vR0 + 96) * 72 + vC]) = vr3;

        // syncB: LDS writes visible; zero outstanding VMEM here -> drain is free
        __syncthreads();

        // issue next tile's prefetch NOW — lands during this step's compute
        {
            int nkb = kb + 64;
            long ko = (nkb < kbend) ? nkb : 0;  // clamp keeps last-iter loads in-bounds
            kr0 = *reinterpret_cast<const int4*>(Kh + (ko + kR0)      * HD_ + kC);
            kr1 = *reinterpret_cast<const int4*>(Kh + (ko + kR0 + 16) * HD_ + kC);
            kr2 = *reinterpret_cast<const int4*>(Kh + (ko + kR0 + 32) * HD_ + kC);
            kr3 = *reinterpret_cast<const int4*>(Kh + (ko + kR0 + 48) * HD_ + kC);
            vr0 = *reinterpret_cast<const int4*>(Vt + (long)(vR0)      * T_ + ko + vC);
            vr1 = *reinterpret_cast<const int4*>(Vt + (long)(vR0 + 32) * T_ + ko + vC);
            vr2 = *reinterpret_cast<const int4*>(Vt + (long)(vR0 + 64) * T_ + ko + vC);
            vr3 = *reinterpret_cast<const int4*>(Vt + (long)(vR0 + 96) * T_ + ko + vC);
        }

        if (kb > qmaxw) continue;  // wave-uniform skip; barriers stay at loop top

        // wave-uniform: tile entirely below the diagonal for this group?
        const bool full0 = (kb + 63) <= (qb + wave * 32);
        const bool full1 = (kb + 63) <= (qb + wave * 32 + 16);

        // S^T = K Q^T for BOTH groups; each kf ds_read feeds 2 MFMAs.
        // s{g}[st][r] = S[key=kb+st*16+quad*4+r][q{g}_abs]
        f32x4 s0[4], s1[4];
#pragma unroll
        for (int st = 0; st < 4; ++st) { s0[st] = zero; s1[st] = zero; }
#pragma unroll
        for (int kk = 0; kk < 4; ++kk) {
#pragma unroll
            for (int st = 0; st < 4; ++st) {
                bf16x8 kf = *reinterpret_cast<const bf16x8*>(
                    &lK[(st * 16 + l16) * 136 + kk * 32 + quad * 8]);
                s0[st] = __builtin_amdgcn_mfma_f32_16x16x32_bf16(kf, aQ0[kk], s0[st], 0, 0, 0);
                s1[st] = __builtin_amdgcn_mfma_f32_16x16x32_bf16(kf, aQ1[kk], s1[st], 0, 0, 0);
            }
        }

        // ---- online softmax, group 0 (lane owns row q0_abs) ----
        {
            float xv[4][4];
            float mx = -1e30f;
            if (full0) {
#pragma unroll
                for (int st = 0; st < 4; ++st)
#pragma unroll
                    for (int r = 0; r < 4; ++r) {
                        float v = s0[st][r] * scl;
                        xv[st][r] = v;
                        mx = fmaxf(mx, v);
                    }
            } else {
#pragma unroll
                for (int st = 0; st < 4; ++st)
#pragma unroll
                    for (int r = 0; r < 4; ++r) {
                        int key = kb + st * 16 + quad * 4 + r;
                        float v = (key <= q0_abs) ? s0[st][r] * scl : -1e30f;
                        xv[st][r] = v;
                        mx = fmaxf(mx, v);
                    }
            }
            mx = fmaxf(mx, __shfl_xor(mx, 16));
            mx = fmaxf(mx, __shfl_xor(mx, 32));
            // T13 defer-max: wave-uniform skip of the rescale
            bool defer = __all(mx - m0_ <= THR);
            float mn = defer ? m0_ : fmaxf(m0_, mx);
            float rs = 0.f;
#pragma unroll
            for (int st = 0; st < 4; ++st)
#pragma unroll
                for (int r = 0; r < 4; ++r) {
                    float e = __expf(xv[st][r] - mn);
                    xv[st][r] = e;
                    rs += e;
                }
            rs += __shfl_xor(rs, 16);
            rs += __shfl_xor(rs, 32);
#pragma unroll
            for (int st = 0; st < 4; ++st) {
                ushort4 pk;
                pk.x = f2bs(xv[st][0]); pk.y = f2bs(xv[st][1]);
                pk.z = f2bs(xv[st][2]); pk.w = f2bs(xv[st][3]);
                *reinterpret_cast<ushort4*>(&lP[wave][0][l16 * 72 + st * 16 + quad * 4]) = pk;
            }
            if (defer) {
                l0_ = l0_ + rs;
            } else {
                float al = __expf(m0_ - mn);
                l0_ = l0_ * al + rs;
                m0_ = mn;
                float alr[4];
#pragma unroll
                for (int r = 0; r < 4; ++r) alr[r] = __shfl(al, quad * 4 + r);
#pragma unroll
                for (int h = 0; h < 8; ++h)
#pragma unroll
                    for (int r = 0; r < 4; ++r) O0[h][r] *= alr[r];
            }
        }
        // ---- online softmax, group 1 ----
        {
            float xv[4][4];
            float mx = -1e30f;
            if (full1) {
#pragma unroll
                for (int st = 0; st < 4; ++st)
#pragma unroll
                    for (int r = 0; r < 4; ++r) {
                        float v = s1[st][r] * scl;
                        xv[st][r] = v;
                        mx = fmaxf(mx, v);
                    }
            } else {
#pragma unroll
                for (int st = 0; st < 4; ++st)
#pragma unroll
                    for (int r = 0; r < 4; ++r) {
                        int key = kb + st * 16 + quad * 4 + r;
                        float v = (key <= q1_abs) ? s1[st][r] * scl : -1e30f;
                        xv[st][r] = v;
                        mx = fmaxf(mx, v);
                    }
            }
            mx = fmaxf(mx, __shfl_xor(mx, 16));
            mx = fmaxf(mx, __shfl_xor(mx, 32));
            bool defer = __all(mx - m1_ <= THR);
            float mn = defer ? m1_ : fmaxf(m1_, mx);
            float rs = 0.f;
#pragma unroll
            for (int st = 0; st < 4; ++st)
#pragma unroll
                for (int r = 0; r < 4; ++r) {
                    float e = __expf(xv[st][r] - mn);
                    xv[st][r] = e;
                    rs += e;
                }
            rs += __shfl_xor(rs, 16);
            rs += __shfl_xor(rs, 32);
#pragma unroll
            for (int st = 0; st < 4; ++st) {
                ushort4 pk;
                pk.x = f2bs(xv[st][0]); pk.y = f2bs(xv[st][1]);
                pk.z = f2bs(xv[st][2]); pk.w = f2bs(xv[st][3]);
                *reinterpret_cast<ushort4*>(&lP[wave][1][l16 * 72 + st * 16 + quad * 4]) = pk;
            }
            if (defer) {
                l1_ = l1_ + rs;
            } else {
                float al = __expf(m1_ - mn);
                l1_ = l1_ * al + rs;
                m1_ = mn;
                float alr[4];
#pragma unroll
                for (int r = 0; r < 4; ++r) alr[r] = __shfl(al, quad * 4 + r);
#pragma unroll
                for (int h = 0; h < 8; ++h)
#pragma unroll
                    for (int r = 0; r < 4; ++r) O1[h][r] *= alr[r];
            }
        }

        // P @ V for BOTH groups; each vf ds_read feeds 2 MFMAs.
#pragma unroll
        for (int kc = 0; kc < 2; ++kc) {
            bf16x8 pf0 = *reinterpret_cast<const bf16x8*>(
                &lP[wave][0][l16 * 72 + kc * 32 + quad * 8]);
            bf16x8 pf1 = *reinterpret_cast<const bf16x8*>(
                &lP[wave][1][l16 * 72 + kc * 32 + quad * 8]);
#pragma unroll
            for (int h = 0; h < 8; ++h) {
                bf16x8 vf = *reinterpret_cast<const bf16x8*>(
                    &lVt[(h * 16 + l16) * 72 + kc * 32 + quad * 8]);
                O0[h] = __builtin_amdgcn_mfma_f32_16x16x32_bf16(pf0, vf, O0[h], 0, 0, 0);
                O1[h] = __builtin_amdgcn_mfma_f32_16x16x32_bf16(pf1, vf, O1[h], 0, 0, 0);
            }
        }
    }

    // write y[b*T+t][hh*128 + hd] bf16; 1/l for row quad*4+r fetched from lane l16=quad*4+r
    int b = bh >> 4, hh = bh & 15;
#pragma unroll
    for (int r = 0; r < 4; ++r) {
        int t0 = qb + wave * 32 + quad * 4 + r;
        float inv0 = 1.f / __shfl(l0_, quad * 4 + r);
#pragma unroll
        for (int h = 0; h < 8; ++h)
            y[(long)(b * T_ + t0) * C_ + hh * HD_ + h * 16 + l16] = f2bs(O0[h][r] * inv0);
        int t1 = t0 + 16;
        float inv1 = 1.f / __shfl(l1_, quad * 4 + r);
#pragma unroll
        for (int h = 0; h < 8; ++h)
            y[(long)(b * T_ + t1) * C_ + hh * HD_ + h * 16 + l16] = f2bs(O1[h][r] * inv1);
    }
}

extern "C" void kernel_launch(void* const* d_in, const int* in_sizes, int n_in,
                              void* d_out, int out_size, void* d_ws, size_t ws_size,
                              hipStream_t stream) {
    const float* x     = (const float*)d_in[0];
    // d_in[1] = causal mask, ignored (handled analytically)
    const float* Wqkv  = (const float*)d_in[2];
    const float* Wproj = (const float*)d_in[3];
    const float* bproj = (const float*)d_in[4];
    float* out = (float*)d_out;

    // workspace layout (bf16 elements); y aliases XB (XB dead after gemm1)
    unsigned short* XB     = (unsigned short*)d_ws;   // [4096][2048]  (later: y)
    unsigned short* WQKVT  = XB + 8388608;            // [6144][2048]
    unsigned short* WPROJT = WQKVT + 12582912;        // [2048][2048]
    unsigned short* QKV    = WPROJT + 4194304;        // [3][32][...]
    if (ws_size < 100663296) return;                  // 96 MB needed

    k_prep<<<12288, 256, 0, stream>>>(x, XB, Wqkv, WQKVT, Wproj, WPROJT);
    k_gemm<0><<<dim3(6144 / 128, 4096 / 128), 256, 0, stream>>>(XB, WQKVT, 4096, 6144, 2048,
                                                                QKV, nullptr, nullptr);
    k_attn<<<dim3(32, 16), 256, 0, stream>>>(QKV, XB);
    k_gemm<1><<<dim3(2048 / 128, 4096 / 128), 256, 0, stream>>>(XB, WPROJT, 4096, 2048, 2048,
                                                                nullptr, out, bproj);
}